// Round 1
// baseline (876.950 us; speedup 1.0000x reference)
//
#include <hip/hip_runtime.h>
#include <hip/hip_bf16.h>

#define VIRTUAL_Z 100

constexpr int D = 150;      // feature dim
constexpr int PAIRS = 75;   // D/2 (float2 pairs per row)
constexpr int A = 128;      // attention hidden dim

// One block per graph segment. batch is sorted, so each segment is a
// contiguous row range found by binary search. 4 waves stride rows; lanes
// cover the row as float2 (pairs 0..63 and 64..74). Real/virtual sums are
// kept in registers, reduced through LDS, means written out, and the HAN
// attention logit for this graph is computed in-block (overlapped with the
// HBM-bound pooling of other blocks) and atomically accumulated.
__global__ __launch_bounds__(256, 4) void pool_att_kernel(
    const float* __restrict__ x, const int* __restrict__ z,
    const int* __restrict__ batch, const float* __restrict__ W1,
    const float* __restrict__ b1v, const float* __restrict__ qv,
    float* __restrict__ meanR, float* __restrict__ meanV,
    float* __restrict__ score, int N)
{
    const int b = blockIdx.x;
    const int t = threadIdx.x;
    const int wave = t >> 6;
    const int lane = t & 63;

    // lower_bound(batch, b) and lower_bound(batch, b+1)
    int lo = 0, hi = N;
    while (lo < hi) { int mid = (lo + hi) >> 1; if (batch[mid] < b) lo = mid + 1; else hi = mid; }
    const int row0 = lo;
    hi = N;
    while (lo < hi) { int mid = (lo + hi) >> 1; if (batch[mid] <= b) lo = mid + 1; else hi = mid; }
    const int row1 = lo;

    float2 aR0 = make_float2(0.f, 0.f), aR1 = make_float2(0.f, 0.f);
    float2 aV0 = make_float2(0.f, 0.f), aV1 = make_float2(0.f, 0.f);
    float cR = 0.f, cV = 0.f;
    const bool l2on = lane < (PAIRS - 64);   // lanes 0..10 carry pairs 64..74

    for (int r = row0 + wave; r < row1; r += 4) {
        const int zr = z[r];                              // wave-uniform
        const float2* row = (const float2*)(x + (size_t)r * D);  // 600B rows: 8B-aligned
        float2 v0 = row[lane];
        float2 v1 = l2on ? row[64 + lane] : make_float2(0.f, 0.f);
        if (zr == VIRTUAL_Z) {
            aV0.x += v0.x; aV0.y += v0.y; aV1.x += v1.x; aV1.y += v1.y; cV += 1.f;
        } else {
            aR0.x += v0.x; aR0.y += v0.y; aR1.x += v1.x; aR1.y += v1.y; cR += 1.f;
        }
    }

    __shared__ float2 part[4][2][PAIRS];
    __shared__ float cnts[4][2];
    __shared__ float mean_f[2][D];
    __shared__ float wpart[4];

    part[wave][0][lane] = aR0;
    part[wave][1][lane] = aV0;
    if (l2on) { part[wave][0][64 + lane] = aR1; part[wave][1][64 + lane] = aV1; }
    if (lane == 0) { cnts[wave][0] = cR; cnts[wave][1] = cV; }
    __syncthreads();

    if (t < 2 * PAIRS) {
        const int m = (t >= PAIRS) ? 1 : 0;
        const int p = t - m * PAIRS;
        float2 s0 = part[0][m][p], s1 = part[1][m][p];
        float2 s2 = part[2][m][p], s3 = part[3][m][p];
        float sx = s0.x + s1.x + s2.x + s3.x;
        float sy = s0.y + s1.y + s2.y + s3.y;
        float c = cnts[0][m] + cnts[1][m] + cnts[2][m] + cnts[3][m];
        float den = fmaxf(c, 1.f);
        float2 mn = make_float2(sx / den, sy / den);
        float* dst = (m == 0) ? meanR : meanV;
        ((float2*)(dst + (size_t)b * D))[p] = mn;
        mean_f[m][2 * p]     = mn.x;
        mean_f[m][2 * p + 1] = mn.y;
    }
    __syncthreads();

    // HAN semantic-attention logit: thread t -> (m = t>>7, a = t&127)
    const int m2 = t >> 7;
    const int a = t & (A - 1);
    float h = b1v[a];
    const float* mrow = mean_f[m2];
    #pragma unroll 6
    for (int d = 0; d < D; ++d) h = fmaf(mrow[d], W1[d * A + a], h);
    float sc = tanhf(h) * qv[a];
    #pragma unroll
    for (int off = 32; off > 0; off >>= 1) sc += __shfl_down(sc, off, 64);
    if (lane == 0) wpart[wave] = sc;
    __syncthreads();
    if (t == 0) {
        atomicAdd(&score[0], wpart[0] + wpart[1]);   // m=0: waves 0,1
        atomicAdd(&score[1], wpart[2] + wpart[3]);   // m=1: waves 2,3
    }
}

// out currently holds the real means; blend in virtual means with
// beta = softmax(mean_b logits) computed inline from the 2 accumulated scores.
__global__ __launch_bounds__(256) void finalize_kernel(
    const float* __restrict__ meanV, const float* __restrict__ score,
    float* out, float invB, int total_pairs)
{
    int idx = blockIdx.x * blockDim.x + threadIdx.x;
    if (idx >= total_pairs) return;
    float s0 = score[0] * invB;
    float s1 = score[1] * invB;
    float mx = fmaxf(s0, s1);
    float e0 = expf(s0 - mx);
    float e1 = expf(s1 - mx);
    float den = e0 + e1;
    float beta0 = e0 / den, beta1 = e1 / den;
    float2 r = ((const float2*)out)[idx];
    float2 v = ((const float2*)meanV)[idx];
    ((float2*)out)[idx] = make_float2(beta0 * r.x + beta1 * v.x,
                                      beta0 * r.y + beta1 * v.y);
}

extern "C" void kernel_launch(void* const* d_in, const int* in_sizes, int n_in,
                              void* d_out, int out_size, void* d_ws, size_t ws_size,
                              hipStream_t stream)
{
    const float* x     = (const float*)d_in[0];   // [N, D]
    const int*   z     = (const int*)d_in[1];     // [N]
    const int*   batch = (const int*)d_in[2];     // [N], sorted
    const float* W1    = (const float*)d_in[3];   // [D, A]
    const float* b1v   = (const float*)d_in[4];   // [A]
    const float* qv    = (const float*)d_in[5];   // [A]

    const int N = in_sizes[1];
    const int B = out_size / D;                   // 4096

    float* meanR = (float*)d_out;                 // [B, D] real means, blended in place
    float* meanV = (float*)d_ws;                  // [B, D] virtual means
    float* score = meanV + (size_t)B * D;         // [2] logit accumulators

    hipMemsetAsync(score, 0, 2 * sizeof(float), stream);
    pool_att_kernel<<<B, 256, 0, stream>>>(x, z, batch, W1, b1v, qv,
                                           meanR, meanV, score, N);
    const int total_pairs = B * PAIRS;
    finalize_kernel<<<(total_pairs + 255) / 256, 256, 0, stream>>>(
        meanV, score, meanR, 1.0f / (float)B, total_pairs);
}

// Round 2
// 838.426 us; speedup vs baseline: 1.0459x; 1.0459x over previous
//
#include <hip/hip_runtime.h>
#include <hip/hip_bf16.h>

#define VIRTUAL_Z 100

constexpr int D = 150;      // feature dim
constexpr int PAIRS = 75;   // D/2 (float2 pairs per row)
constexpr int A = 128;      // attention hidden dim

// One block per graph segment. batch is sorted, so each segment is a
// contiguous row range found by binary search. 4 waves stride rows; lanes
// cover the row as float2 (pairs 0..63 and 64..74).
// Branchless accumulation: sumAll unconditionally, sumV via fmaf with a
// 0/1 mask from z -- no z-dependent branch, so row loads pipeline freely.
// real = all - virtual at reduction time.
__global__ __launch_bounds__(256, 4) void pool_att_kernel(
    const float* __restrict__ x, const int* __restrict__ z,
    const int* __restrict__ batch, const float* __restrict__ W1,
    const float* __restrict__ b1v, const float* __restrict__ qv,
    float* __restrict__ meanR, float* __restrict__ meanV,
    float* __restrict__ score, int N)
{
    const int b = blockIdx.x;
    const int t = threadIdx.x;
    const int wave = t >> 6;
    const int lane = t & 63;

    // lower_bound(batch, b) and lower_bound(batch, b+1)
    int lo = 0, hi = N;
    while (lo < hi) { int mid = (lo + hi) >> 1; if (batch[mid] < b) lo = mid + 1; else hi = mid; }
    const int row0 = lo;
    hi = N;
    while (lo < hi) { int mid = (lo + hi) >> 1; if (batch[mid] <= b) lo = mid + 1; else hi = mid; }
    const int row1 = lo;

    float2 sA0 = make_float2(0.f, 0.f), sA1 = make_float2(0.f, 0.f);
    float2 sV0 = make_float2(0.f, 0.f), sV1 = make_float2(0.f, 0.f);
    float cA = 0.f, cV = 0.f;
    const bool l2on = lane < (PAIRS - 64);   // lanes 0..10 carry pairs 64..74

    #pragma unroll 2
    for (int r = row0 + wave; r < row1; r += 4) {
        const float m = (z[r] == VIRTUAL_Z) ? 1.0f : 0.0f;   // wave-uniform
        const float2* row = (const float2*)(x + (size_t)r * D);
        float2 v0 = row[lane];
        float2 v1 = l2on ? row[64 + lane] : make_float2(0.f, 0.f);
        sA0.x += v0.x; sA0.y += v0.y;
        sA1.x += v1.x; sA1.y += v1.y;
        sV0.x = fmaf(m, v0.x, sV0.x); sV0.y = fmaf(m, v0.y, sV0.y);
        sV1.x = fmaf(m, v1.x, sV1.x); sV1.y = fmaf(m, v1.y, sV1.y);
        cA += 1.f; cV += m;
    }

    __shared__ float2 part[4][2][PAIRS];   // [wave][all|virt][pair]
    __shared__ float cnts[4][2];
    __shared__ float mean_f[2][D];
    __shared__ float wpart[4];

    part[wave][0][lane] = sA0;
    part[wave][1][lane] = sV0;
    if (l2on) { part[wave][0][64 + lane] = sA1; part[wave][1][64 + lane] = sV1; }
    if (lane == 0) { cnts[wave][0] = cA; cnts[wave][1] = cV; }
    __syncthreads();

    if (t < 2 * PAIRS) {
        const int m = (t >= PAIRS) ? 1 : 0;   // 0 = real, 1 = virtual
        const int p = t - m * PAIRS;
        float2 a0 = part[0][0][p], a1 = part[1][0][p], a2 = part[2][0][p], a3 = part[3][0][p];
        float2 v0 = part[0][1][p], v1 = part[1][1][p], v2 = part[2][1][p], v3 = part[3][1][p];
        float vx = v0.x + v1.x + v2.x + v3.x;
        float vy = v0.y + v1.y + v2.y + v3.y;
        float cAll = cnts[0][0] + cnts[1][0] + cnts[2][0] + cnts[3][0];
        float cVir = cnts[0][1] + cnts[1][1] + cnts[2][1] + cnts[3][1];
        float sx, sy, c;
        if (m == 0) {   // real = all - virtual
            sx = (a0.x + a1.x + a2.x + a3.x) - vx;
            sy = (a0.y + a1.y + a2.y + a3.y) - vy;
            c = cAll - cVir;
        } else {
            sx = vx; sy = vy; c = cVir;
        }
        float den = fmaxf(c, 1.f);
        float2 mn = make_float2(sx / den, sy / den);
        float* dst = (m == 0) ? meanR : meanV;
        ((float2*)(dst + (size_t)b * D))[p] = mn;
        mean_f[m][2 * p]     = mn.x;
        mean_f[m][2 * p + 1] = mn.y;
    }
    __syncthreads();

    // HAN semantic-attention logit: thread t -> (m = t>>7, a = t&127)
    const int m2 = t >> 7;
    const int a = t & (A - 1);
    float h = b1v[a];
    const float* mrow = mean_f[m2];
    #pragma unroll 6
    for (int d = 0; d < D; ++d) h = fmaf(mrow[d], W1[d * A + a], h);
    float sc = tanhf(h) * qv[a];
    #pragma unroll
    for (int off = 32; off > 0; off >>= 1) sc += __shfl_down(sc, off, 64);
    if (lane == 0) wpart[wave] = sc;
    __syncthreads();
    if (t == 0) {
        atomicAdd(&score[0], wpart[0] + wpart[1]);   // m=0: waves 0,1
        atomicAdd(&score[1], wpart[2] + wpart[3]);   // m=1: waves 2,3
    }
}

// out currently holds the real means; blend in virtual means with
// beta = softmax(mean_b logits) computed inline from the 2 accumulated scores.
__global__ __launch_bounds__(256) void finalize_kernel(
    const float* __restrict__ meanV, const float* __restrict__ score,
    float* out, float invB, int total_pairs)
{
    int idx = blockIdx.x * blockDim.x + threadIdx.x;
    if (idx >= total_pairs) return;
    float s0 = score[0] * invB;
    float s1 = score[1] * invB;
    float mx = fmaxf(s0, s1);
    float e0 = expf(s0 - mx);
    float e1 = expf(s1 - mx);
    float den = e0 + e1;
    float beta0 = e0 / den, beta1 = e1 / den;
    float2 r = ((const float2*)out)[idx];
    float2 v = ((const float2*)meanV)[idx];
    ((float2*)out)[idx] = make_float2(beta0 * r.x + beta1 * v.x,
                                      beta0 * r.y + beta1 * v.y);
}

extern "C" void kernel_launch(void* const* d_in, const int* in_sizes, int n_in,
                              void* d_out, int out_size, void* d_ws, size_t ws_size,
                              hipStream_t stream)
{
    const float* x     = (const float*)d_in[0];   // [N, D]
    const int*   z     = (const int*)d_in[1];     // [N]
    const int*   batch = (const int*)d_in[2];     // [N], sorted
    const float* W1    = (const float*)d_in[3];   // [D, A]
    const float* b1v   = (const float*)d_in[4];   // [A]
    const float* qv    = (const float*)d_in[5];   // [A]

    const int N = in_sizes[1];
    const int B = out_size / D;                   // 4096

    float* meanR = (float*)d_out;                 // [B, D] real means, blended in place
    float* meanV = (float*)d_ws;                  // [B, D] virtual means
    float* score = meanV + (size_t)B * D;         // [2] logit accumulators

    hipMemsetAsync(score, 0, 2 * sizeof(float), stream);
    pool_att_kernel<<<B, 256, 0, stream>>>(x, z, batch, W1, b1v, qv,
                                           meanR, meanV, score, N);
    const int total_pairs = B * PAIRS;
    finalize_kernel<<<(total_pairs + 255) / 256, 256, 0, stream>>>(
        meanV, score, meanR, 1.0f / (float)B, total_pairs);
}